// Round 13
// baseline (253.904 us; speedup 1.0000x reference)
//
#include <hip/hip_runtime.h>
#include <hip/hip_bf16.h>

// ---------------------------------------------------------------------------
// GAT 2-layer forward on MI355X.  8 dispatches total.
//   k_prep: W split (both layers) + zero counters
//   k_gemm_hist: layer-1 MFMA gemm  ∥  bucket histogram + last-block scan
//   k_bukscatter -> k_csr: CSR (esrc only, self-loop last per node)
//   k_agg (fused att-coef + paired-edge gather agg)  x2 layers
//   k_gemm_mfma: layer-2 gemm
//   k_pool: partial sums + last-block-per-graph reduce + logits
// ---------------------------------------------------------------------------

#define THREADS 256
#define PSLICE 16
#define BUK_S 196        // nodes per bucket (NBUK = 256 for N=50000)
#define SORT_BLOCKS 128

typedef __attribute__((ext_vector_type(8))) short short8v;   // 8 bf16
typedef __attribute__((ext_vector_type(4))) float f32x4;

static __device__ __forceinline__ unsigned short f2bf(float f) {
    unsigned int u = __float_as_uint(f);
    return (unsigned short)((u + 0x7fffu + ((u >> 16) & 1u)) >> 16);  // RNE
}
static __device__ __forceinline__ float bf2f(unsigned short b) {
    return __uint_as_float(((unsigned int)b) << 16);
}

// ---- prep: W split + fragment-major reorder (both layers) + zero counters ----
__global__ __launch_bounds__(THREADS) void k_prep(const float* __restrict__ W1,
                                                  const float* __restrict__ W2,
                                                  unsigned short* __restrict__ Wh1,
                                                  unsigned short* __restrict__ Wl1,
                                                  unsigned short* __restrict__ Wh2,
                                                  unsigned short* __restrict__ Wl2,
                                                  int* __restrict__ bcount, int nbuk,
                                                  int* __restrict__ done,
                                                  int* __restrict__ pdone, int ng) {
    if (blockIdx.x == 0) {
        if (threadIdx.x < nbuk) bcount[threadIdx.x] = 0;
        if (threadIdx.x == 0) *done = 0;
        if (threadIdx.x < ng) pdone[threadIdx.x] = 0;
    }
    int t = blockIdx.x * THREADS + threadIdx.x;
    const float* W = W1;
    unsigned short* Wh = Wh1;
    unsigned short* Wl = Wl1;
    if (t >= 128 * 128) {
        t -= 128 * 128;
        W = W2; Wh = Wh2; Wl = Wl2;
    }
    int k = t >> 7, n = t & 127;
    float w = W[t];
    unsigned short h = f2bf(w);
    unsigned short lo = f2bf(w - bf2f(h));
    int c = n >> 4, nl = n & 15, tt = k >> 5, kk = k & 31, g = kk >> 3, j = kk & 7;
    int o = (((c * 4 + tt) * 64) + g * 16 + nl) * 8 + j;
    Wh[o] = h;
    Wl[o] = lo;
}

// swizzled LDS index (ushort units) for x tiles
static __device__ __forceinline__ int xsw(int r, int c) {
    return (((r * 16 + (c >> 3)) ^ (r & 7)) << 3) | (c & 7);
}

// shared MFMA split-bf16 gemm body (64 rows x 128 cols per block)
static __device__ __forceinline__ void gemm_body(unsigned short* xh, unsigned short* xl,
                                                 const float* __restrict__ X,
                                                 const int* __restrict__ idx,
                                                 const unsigned short* __restrict__ WBh,
                                                 const unsigned short* __restrict__ WBl,
                                                 const float* __restrict__ a_s,
                                                 const float* __restrict__ a_d,
                                                 unsigned short* __restrict__ outb,
                                                 float* __restrict__ as_,
                                                 float* __restrict__ ad_,
                                                 int Nrows, int bid) {
    {
        int r = threadIdx.x >> 2;            // 0..63
        int c0 = (threadIdx.x & 3) * 32;
        int R = bid * 64 + r;
        if (R < Nrows) {
            int g = idx ? idx[R] : R;
            const float4* xrow = (const float4*)(X + (size_t)g * 128);
            #pragma unroll
            for (int i = 0; i < 8; ++i) {
                float4 v = xrow[(c0 >> 2) + i];
                int c = c0 + i * 4;
                ushort4 hh, ll;
                hh.x = f2bf(v.x); ll.x = f2bf(v.x - bf2f(hh.x));
                hh.y = f2bf(v.y); ll.y = f2bf(v.y - bf2f(hh.y));
                hh.z = f2bf(v.z); ll.z = f2bf(v.z - bf2f(hh.z));
                hh.w = f2bf(v.w); ll.w = f2bf(v.w - bf2f(hh.w));
                int o = xsw(r, c);
                *(ushort4*)&xh[o] = hh;
                *(ushort4*)&xl[o] = ll;
            }
        } else {
            #pragma unroll
            for (int i = 0; i < 8; ++i) {
                int o = xsw(r, c0 + i * 4);
                *(ushort4*)&xh[o] = make_ushort4(0, 0, 0, 0);
                *(ushort4*)&xl[o] = make_ushort4(0, 0, 0, 0);
            }
        }
    }
    __syncthreads();

    int wid = threadIdx.x >> 6;
    int lane = threadIdx.x & 63;
    int nl = lane & 15;
    int g = lane >> 4;
    int arow = wid * 16 + nl;

    f32x4 acc[8];
    #pragma unroll
    for (int c = 0; c < 8; ++c) acc[c] = (f32x4){0.f, 0.f, 0.f, 0.f};

    #pragma unroll
    for (int t = 0; t < 4; ++t) {
        int ao = xsw(arow, t * 32 + g * 8);
        short8v ah = *(const short8v*)&xh[ao];
        short8v al = *(const short8v*)&xl[ao];
        #pragma unroll
        for (int c = 0; c < 8; ++c) {
            int bo = (((c * 4 + t) * 64) + lane) * 8;
            short8v bh = *(const short8v*)&WBh[bo];
            short8v bl = *(const short8v*)&WBl[bo];
            acc[c] = __builtin_amdgcn_mfma_f32_16x16x32_bf16(ah, bh, acc[c], 0, 0, 0);
            acc[c] = __builtin_amdgcn_mfma_f32_16x16x32_bf16(ah, bl, acc[c], 0, 0, 0);
            acc[c] = __builtin_amdgcn_mfma_f32_16x16x32_bf16(al, bh, acc[c], 0, 0, 0);
        }
    }

    float asv[8], adv[8];
    #pragma unroll
    for (int c = 0; c < 8; ++c) {
        asv[c] = a_s[c * 16 + nl];
        adv[c] = a_d[c * 16 + nl];
    }
    int Rb = bid * 64 + wid * 16 + g * 4;
    #pragma unroll
    for (int r = 0; r < 4; ++r) {
        int R = Rb + r;
        bool ok = (R < Nrows);
        float ps = 0.f, pd = 0.f;
        #pragma unroll
        for (int c = 0; c < 8; ++c) {
            float v = acc[c][r];
            if (ok) outb[(size_t)R * 128 + c * 16 + nl] = f2bf(v);
            ps = fmaf(v, asv[c], ps);
            pd = fmaf(v, adv[c], pd);
        }
        #pragma unroll
        for (int o = 8; o; o >>= 1) {
            ps += __shfl_xor(ps, o);
            pd += __shfl_xor(pd, o);
        }
        if (ok && nl == 0) {
            as_[R] = ps;
            ad_[R] = pd;
        }
    }
}

// ---- layer-1 gemm ∥ bucket histogram; last hist block performs the scans ----
__global__ __launch_bounds__(THREADS) void k_gemm_hist(const float* __restrict__ X,
                                                       const int* __restrict__ idx,
                                                       const unsigned short* __restrict__ WBh,
                                                       const unsigned short* __restrict__ WBl,
                                                       const float* __restrict__ a_s,
                                                       const float* __restrict__ a_d,
                                                       unsigned short* __restrict__ outb,
                                                       float* __restrict__ as_,
                                                       float* __restrict__ ad_,
                                                       int Nrows, int gemm_blocks,
                                                       const int* __restrict__ dst,
                                                       int* __restrict__ bcount,
                                                       int E_, int chunk,
                                                       int* __restrict__ done,
                                                       int* __restrict__ sbase,
                                                       int* __restrict__ gcur,
                                                       int* __restrict__ cbase,
                                                       int nbuk, int Nn) {
    __shared__ unsigned short xh[64 * 128];
    __shared__ unsigned short xl[64 * 128];
    if ((int)blockIdx.x >= gemm_blocks) {
        int hbk = blockIdx.x - gemm_blocks;
        int tid = threadIdx.x;
        __shared__ int hist[THREADS];
        hist[tid] = 0;
        __syncthreads();
        int e0 = hbk * chunk;
        int e1 = min(e0 + chunk, E_);
        for (int e = e0 + tid; e < e1; e += THREADS)
            atomicAdd(&hist[dst[e] / BUK_S], 1);
        __syncthreads();
        int c = hist[tid];
        if (c) atomicAdd(&bcount[tid], c);
        __threadfence();
        __syncthreads();
        __shared__ int lastf;
        if (tid == 0) lastf = (atomicAdd(done, 1) == SORT_BLOCKS - 1);
        __syncthreads();
        if (!lastf) return;
        __threadfence();
        // scans (sole surviving block; bcount via device-scope atomic loads)
        __shared__ int s2[THREADS];
        int v = 0;
        if (tid < nbuk) v = __hip_atomic_load(&bcount[tid], __ATOMIC_RELAXED, __HIP_MEMORY_SCOPE_AGENT);
        s2[tid] = v;
        __syncthreads();
        for (int off = 1; off < THREADS; off <<= 1) {
            int t = (tid >= off) ? s2[tid - off] : 0;
            __syncthreads();
            s2[tid] += t;
            __syncthreads();
        }
        int excl1 = s2[tid] - v;
        if (tid < nbuk) { sbase[tid] = excl1; gcur[tid] = excl1; }
        int n0 = tid * BUK_S;
        int ns = (tid < nbuk) ? min(BUK_S, Nn - n0) : 0;
        int v2 = v + ns;
        __syncthreads();
        s2[tid] = v2;
        __syncthreads();
        for (int off = 1; off < THREADS; off <<= 1) {
            int t = (tid >= off) ? s2[tid - off] : 0;
            __syncthreads();
            s2[tid] += t;
            __syncthreads();
        }
        if (tid < nbuk) cbase[tid] = s2[tid] - v2;
        return;
    }
    gemm_body(xh, xl, X, idx, WBh, WBl, a_s, a_d, outb, as_, ad_, Nrows, blockIdx.x);
}

// ---- plain layer-2 gemm ----
__global__ __launch_bounds__(THREADS) void k_gemm_mfma(const float* __restrict__ X,
                                                       const unsigned short* __restrict__ WBh,
                                                       const unsigned short* __restrict__ WBl,
                                                       const float* __restrict__ a_s,
                                                       const float* __restrict__ a_d,
                                                       unsigned short* __restrict__ outb,
                                                       float* __restrict__ as_,
                                                       float* __restrict__ ad_, int Nrows) {
    __shared__ unsigned short xh[64 * 128];
    __shared__ unsigned short xl[64 * 128];
    gemm_body(xh, xl, X, nullptr, WBh, WBl, a_s, a_d, outb, as_, ad_, Nrows, blockIdx.x);
}

// ---- coarse scatter of packed records into bucket staging ----
__global__ __launch_bounds__(THREADS) void k_bukscatter(const int* __restrict__ src,
                                                        const int* __restrict__ dst,
                                                        int* __restrict__ gcur,
                                                        unsigned int* __restrict__ rec,
                                                        int E_, int chunk) {
    __shared__ int hist[THREADS];
    __shared__ int base[THREADS];
    hist[threadIdx.x] = 0;
    __syncthreads();
    int e0 = blockIdx.x * chunk;
    int e1 = min(e0 + chunk, E_);
    for (int e = e0 + threadIdx.x; e < e1; e += THREADS)
        atomicAdd(&hist[dst[e] / BUK_S], 1);
    __syncthreads();
    int c = hist[threadIdx.x];
    if (c) base[threadIdx.x] = atomicAdd(&gcur[threadIdx.x], c);
    hist[threadIdx.x] = 0;
    __syncthreads();
    for (int e = e0 + threadIdx.x; e < e1; e += THREADS) {
        int d = dst[e];
        int b = d / BUK_S;
        int r = atomicAdd(&hist[b], 1);
        rec[base[b] + r] = (unsigned int)src[e] | ((unsigned int)(d - b * BUK_S) << 17);
    }
}

// ---- per-bucket fine pass -> rowptr + esrc (self-loop last slot) ----
__global__ __launch_bounds__(THREADS) void k_csr(const unsigned int* __restrict__ rec,
                                                 const int* __restrict__ sbase,
                                                 const int* __restrict__ bcount,
                                                 const int* __restrict__ cbase,
                                                 int* __restrict__ rowptr,
                                                 int* __restrict__ esrc,
                                                 int Nn, int nbuk, int Etot) {
    __shared__ int cnt[THREADS];
    __shared__ int s[THREADS];
    __shared__ int cur[THREADS];
    int b = blockIdx.x;
    int tid = threadIdx.x;
    int n0 = b * BUK_S;
    int ns = min(BUK_S, Nn - n0);
    int cnt_e = bcount[b];
    int rbase = sbase[b];
    int cb = cbase[b];

    cnt[tid] = 0;
    __syncthreads();
    for (int i = tid; i < cnt_e; i += THREADS)
        atomicAdd(&cnt[rec[rbase + i] >> 17], 1);
    __syncthreads();
    int v = (tid < ns) ? cnt[tid] + 1 : 0;   // +1 self-loop
    s[tid] = v;
    __syncthreads();
    for (int off = 1; off < THREADS; off <<= 1) {
        int t = (tid >= off) ? s[tid - off] : 0;
        __syncthreads();
        s[tid] += t;
        __syncthreads();
    }
    int excl = s[tid] - v;
    __syncthreads();
    s[tid] = excl;
    cur[tid] = excl;
    if (tid < ns) rowptr[n0 + tid] = cb + excl;
    if (b == nbuk - 1 && tid == 0) rowptr[Nn] = Etot;
    __syncthreads();
    for (int i = tid; i < cnt_e; i += THREADS) {
        unsigned int r = rec[rbase + i];
        int l = r >> 17;
        int slot = atomicAdd(&cur[l], 1);
        esrc[cb + slot] = (int)(r & 0x1FFFFu);
    }
    __syncthreads();
    if (tid < ns) esrc[cb + s[tid] + cnt[tid]] = n0 + tid;   // self-loop last
}

// wave per dst node, fused attention-coef + aggregation (unchanged from R12).
__global__ __launch_bounds__(THREADS) void k_agg(const unsigned short* __restrict__ hb,
                                                 const float* __restrict__ as_,
                                                 const float* __restrict__ ad_,
                                                 const int* __restrict__ rowptr,
                                                 const int* __restrict__ esrc,
                                                 const float* __restrict__ bias,
                                                 float* __restrict__ out, int Nn) {
    __shared__ int2 ep[4][64];
    int w = threadIdx.x >> 6;
    int lane = threadIdx.x & 63;
    int half = lane >> 5;    // which edge of the pair
    int j = lane & 31;       // dim group (4 dims per lane)
    int d = blockIdx.x * 4 + w;
    if (d >= Nn) return;
    int beg = rowptr[d], end = rowptr[d + 1];
    float adv = ad_[d];
    float z = 0.f, a0 = 0.f, a1 = 0.f, a2 = 0.f, a3 = 0.f;
    for (int c0 = beg; c0 < end; c0 += 64) {
        int kk = c0 + lane;
        bool ok = (kk < end);
        int sl = esrc[ok ? kk : beg];
        float pv = 0.f;
        if (ok) {
            float e = as_[sl] + adv;
            e = (e > 0.f) ? e : 0.2f * e;
            pv = __expf(e);
        }
        ep[w][lane] = make_int2(sl, __float_as_int(pv));
        int cn = end - c0;
        if (cn > 64) cn = 64;
        for (int k0 = 0; k0 < cn; k0 += 16) {
            int2 ev[8];
            #pragma unroll
            for (int i = 0; i < 8; ++i)
                ev[i] = ep[w][(k0 + 2 * i + half) & 63];   // p=0 past cn
            uint2 hv[8];
            #pragma unroll
            for (int i = 0; i < 8; ++i)
                hv[i] = *(const uint2*)&hb[((size_t)ev[i].x << 7) + j * 4];
            #pragma unroll
            for (int i = 0; i < 8; ++i) {
                float p = __int_as_float(ev[i].y);
                z += p;
                a0 += p * __uint_as_float(hv[i].x << 16);
                a1 += p * __uint_as_float(hv[i].x & 0xffff0000u);
                a2 += p * __uint_as_float(hv[i].y << 16);
                a3 += p * __uint_as_float(hv[i].y & 0xffff0000u);
            }
        }
    }
    z  += __shfl_xor(z, 32);
    a0 += __shfl_xor(a0, 32);
    a1 += __shfl_xor(a1, 32);
    a2 += __shfl_xor(a2, 32);
    a3 += __shfl_xor(a3, 32);
    if (half == 0) {
        float inv = 1.f / z;
        float4 o;
        o.x = fmaxf(a0 * inv + bias[j * 4 + 0], 0.f);
        o.y = fmaxf(a1 * inv + bias[j * 4 + 1], 0.f);
        o.z = fmaxf(a2 * inv + bias[j * 4 + 2], 0.f);
        o.w = fmaxf(a3 * inv + bias[j * 4 + 3], 0.f);
        *(float4*)&out[(size_t)d * 128 + j * 4] = o;
    }
}

// ---- fused pool: grid (G, PSLICE) partials; last block per graph reduces
// 16 partials, writes mean + logits ----
__global__ __launch_bounds__(THREADS) void k_pool(const float* __restrict__ x,
                                                  const int* __restrict__ batch,
                                                  float* __restrict__ part,
                                                  int* __restrict__ pdone,
                                                  const float* __restrict__ Wc,
                                                  const float* __restrict__ bc,
                                                  float* __restrict__ out, int Nn, int Gn) {
    int g = blockIdx.x;
    int s = blockIdx.y;
    int a = 0, b = Nn;
    while (a < b) { int mid = (a + b) >> 1; if (batch[mid] < g) a = mid + 1; else b = mid; }
    int lo = a;
    b = Nn;
    while (a < b) { int mid = (a + b) >> 1; if (batch[mid] < g + 1) a = mid + 1; else b = mid; }
    int hi = a;

    __shared__ float sred[THREADS];
    int j = threadIdx.x & 127;
    int half = threadIdx.x >> 7;
    float acc = 0.f;
    for (int n = lo + s * 2 + half; n < hi; n += 2 * PSLICE) acc += x[(size_t)n * 128 + j];
    sred[threadIdx.x] = acc;
    __syncthreads();
    if (half == 0) part[((size_t)g * PSLICE + s) * 128 + j] = sred[j] + sred[128 + j];
    __threadfence();
    __syncthreads();
    __shared__ int lastf;
    if (threadIdx.x == 0) lastf = (atomicAdd(&pdone[g], 1) == PSLICE - 1);
    __syncthreads();
    if (!lastf) return;
    __threadfence();
    int cnt = hi - lo;
    float mean = 0.f;
    if (half == 0) {
        float ssum = 0.f;
        #pragma unroll
        for (int t = 0; t < PSLICE; ++t)
            ssum += __hip_atomic_load(&part[((size_t)g * PSLICE + t) * 128 + j],
                                      __ATOMIC_RELAXED, __HIP_MEMORY_SCOPE_AGENT);
        mean = ssum / fmaxf((float)cnt, 1.f);
        out[Gn + (size_t)g * 128 + j] = mean;
    }
    __syncthreads();
    if (half == 0) sred[j] = mean * Wc[j];
    __syncthreads();
    for (int off = 64; off >= 1; off >>= 1) {
        if (threadIdx.x < off) sred[threadIdx.x] += sred[threadIdx.x + off];
        __syncthreads();
    }
    if (threadIdx.x == 0) out[g] = sred[0] + bc[0];
}

static inline size_t align256(size_t x) { return (x + 255) & ~(size_t)255; }

extern "C" void kernel_launch(void* const* d_in, const int* in_sizes, int n_in,
                              void* d_out, int out_size, void* d_ws, size_t ws_size,
                              hipStream_t stream) {
    const int* x_lex = (const int*)d_in[0];
    const int* eidx  = (const int*)d_in[1];
    const int* batch = (const int*)d_in[2];
    const float* emb = (const float*)d_in[3];
    const float* W1  = (const float*)d_in[4];
    const float* a_s1 = (const float*)d_in[5];
    const float* a_d1 = (const float*)d_in[6];
    const float* b1  = (const float*)d_in[7];
    const float* W2  = (const float*)d_in[8];
    const float* a_s2 = (const float*)d_in[9];
    const float* a_d2 = (const float*)d_in[10];
    const float* b2  = (const float*)d_in[11];
    const float* Wc  = (const float*)d_in[12];
    const float* bc  = (const float*)d_in[13];

    const int N = in_sizes[0];
    const int E = in_sizes[1] / 2;
    const int G = out_size / 129;      // out = [G logits] + [G x 128 pool]
    const int Etot = E + N;
    const int* esrc_in = eidx;
    const int* edst_in = eidx + E;
    const int NBUK = (N + BUK_S - 1) / BUK_S;   // 256 for N=50000

    // workspace carve
    char* p = (char*)d_ws;
    unsigned short* hb = (unsigned short*)p;  p += align256((size_t)N * 128 * 2);
    float* obuf = (float*)p;            p += align256((size_t)N * 128 * 4);
    float* as_  = (float*)p;            p += align256((size_t)N * 4);
    float* ad_  = (float*)p;            p += align256((size_t)N * 4);
    int* bcount = (int*)p;              p += align256((size_t)NBUK * 4);
    int* sbase  = (int*)p;              p += align256((size_t)NBUK * 4);
    int* gcur   = (int*)p;              p += align256((size_t)NBUK * 4);
    int* cbase  = (int*)p;              p += align256((size_t)NBUK * 4);
    int* done   = (int*)p;              p += align256(256);
    int* pdone  = (int*)p;              p += align256((size_t)G * 4);
    int* rowptr = (int*)p;              p += align256((size_t)(N + 1) * 4);
    unsigned int* rec = (unsigned int*)p; p += align256((size_t)Etot * 4);
    int* esrc   = (int*)p;              p += align256((size_t)Etot * 4);
    float* part = (float*)p;            p += align256((size_t)G * PSLICE * 128 * 4);
    unsigned short* WBh1 = (unsigned short*)p; p += align256((size_t)128 * 128 * 2);
    unsigned short* WBl1 = (unsigned short*)p; p += align256((size_t)128 * 128 * 2);
    unsigned short* WBh2 = (unsigned short*)p; p += align256((size_t)128 * 128 * 2);
    unsigned short* WBl2 = (unsigned short*)p; p += align256((size_t)128 * 128 * 2);

    const int chunk = (E + SORT_BLOCKS - 1) / SORT_BLOCKS;
    const int gemm_grid = (N + 63) / 64;
    const int agg_grid = (N + 3) / 4;

    // 1. prep: W split + zero counters
    k_prep<<<128, THREADS, 0, stream>>>(W1, W2, WBh1, WBl1, WBh2, WBl2, bcount, NBUK, done, pdone, G);

    // 2. layer-1 gemm ∥ bucket hist (+ last-block scan)
    k_gemm_hist<<<gemm_grid + SORT_BLOCKS, THREADS, 0, stream>>>(
        emb, x_lex, WBh1, WBl1, a_s1, a_d1, hb, as_, ad_, N, gemm_grid,
        edst_in, bcount, E, chunk, done, sbase, gcur, cbase, NBUK, N);

    // 3-4. CSR build
    k_bukscatter<<<SORT_BLOCKS, THREADS, 0, stream>>>(esrc_in, edst_in, gcur, rec, E, chunk);
    k_csr<<<NBUK, THREADS, 0, stream>>>(rec, sbase, bcount, cbase, rowptr, esrc, N, NBUK, Etot);

    // 5. layer-1 agg
    k_agg<<<agg_grid, THREADS, 0, stream>>>(hb, as_, ad_, rowptr, esrc, b1, obuf, N);

    // 6-7. layer 2
    k_gemm_mfma<<<gemm_grid, THREADS, 0, stream>>>(obuf, WBh2, WBl2, a_s2, a_d2, hb, as_, ad_, N);
    k_agg<<<agg_grid, THREADS, 0, stream>>>(hb, as_, ad_, rowptr, esrc, b2, obuf, N);

    // 8. fused pool + logits
    k_pool<<<dim3(G, PSLICE), THREADS, 0, stream>>>(obuf, batch, part, pdone, Wc, bc, (float*)d_out, N, G);
}

// Round 14
// 189.344 us; speedup vs baseline: 1.3410x; 1.3410x over previous
//
#include <hip/hip_runtime.h>
#include <hip/hip_bf16.h>

// ---------------------------------------------------------------------------
// GAT 2-layer forward on MI355X.  9 dispatches total.
//   k_prep: W split (both layers) + zero counters
//   k_gemm_hist: layer-1 MFMA gemm  ∥  bucket histogram + last-block scan
//   k_bukscatter -> k_csr: CSR (esrc only, self-loop last per node)
//   k_agg (fused att-coef + paired-edge gather agg)  x2 layers
//   k_gemm_mfma: layer-2 gemm
//   k_pool_partial + k_pool_final: pooling + logits (2 dispatches; fused
//   single-dispatch version needs per-block device fences -> 13x slower, R13)
// ---------------------------------------------------------------------------

#define THREADS 256
#define PSLICE 16
#define BUK_S 196        // nodes per bucket (NBUK = 256 for N=50000)
#define SORT_BLOCKS 128

typedef __attribute__((ext_vector_type(8))) short short8v;   // 8 bf16
typedef __attribute__((ext_vector_type(4))) float f32x4;

static __device__ __forceinline__ unsigned short f2bf(float f) {
    unsigned int u = __float_as_uint(f);
    return (unsigned short)((u + 0x7fffu + ((u >> 16) & 1u)) >> 16);  // RNE
}
static __device__ __forceinline__ float bf2f(unsigned short b) {
    return __uint_as_float(((unsigned int)b) << 16);
}

// ---- prep: W split + fragment-major reorder (both layers) + zero counters ----
__global__ __launch_bounds__(THREADS) void k_prep(const float* __restrict__ W1,
                                                  const float* __restrict__ W2,
                                                  unsigned short* __restrict__ Wh1,
                                                  unsigned short* __restrict__ Wl1,
                                                  unsigned short* __restrict__ Wh2,
                                                  unsigned short* __restrict__ Wl2,
                                                  int* __restrict__ bcount, int nbuk,
                                                  int* __restrict__ done) {
    if (blockIdx.x == 0) {
        if (threadIdx.x < nbuk) bcount[threadIdx.x] = 0;
        if (threadIdx.x == 0) *done = 0;
    }
    int t = blockIdx.x * THREADS + threadIdx.x;
    const float* W = W1;
    unsigned short* Wh = Wh1;
    unsigned short* Wl = Wl1;
    if (t >= 128 * 128) {
        t -= 128 * 128;
        W = W2; Wh = Wh2; Wl = Wl2;
    }
    int k = t >> 7, n = t & 127;
    float w = W[t];
    unsigned short h = f2bf(w);
    unsigned short lo = f2bf(w - bf2f(h));
    int c = n >> 4, nl = n & 15, tt = k >> 5, kk = k & 31, g = kk >> 3, j = kk & 7;
    int o = (((c * 4 + tt) * 64) + g * 16 + nl) * 8 + j;
    Wh[o] = h;
    Wl[o] = lo;
}

// swizzled LDS index (ushort units) for x tiles
static __device__ __forceinline__ int xsw(int r, int c) {
    return (((r * 16 + (c >> 3)) ^ (r & 7)) << 3) | (c & 7);
}

// shared MFMA split-bf16 gemm body (64 rows x 128 cols per block)
static __device__ __forceinline__ void gemm_body(unsigned short* xh, unsigned short* xl,
                                                 const float* __restrict__ X,
                                                 const int* __restrict__ idx,
                                                 const unsigned short* __restrict__ WBh,
                                                 const unsigned short* __restrict__ WBl,
                                                 const float* __restrict__ a_s,
                                                 const float* __restrict__ a_d,
                                                 unsigned short* __restrict__ outb,
                                                 float* __restrict__ as_,
                                                 float* __restrict__ ad_,
                                                 int Nrows, int bid) {
    {
        int r = threadIdx.x >> 2;            // 0..63
        int c0 = (threadIdx.x & 3) * 32;
        int R = bid * 64 + r;
        if (R < Nrows) {
            int g = idx ? idx[R] : R;
            const float4* xrow = (const float4*)(X + (size_t)g * 128);
            #pragma unroll
            for (int i = 0; i < 8; ++i) {
                float4 v = xrow[(c0 >> 2) + i];
                int c = c0 + i * 4;
                ushort4 hh, ll;
                hh.x = f2bf(v.x); ll.x = f2bf(v.x - bf2f(hh.x));
                hh.y = f2bf(v.y); ll.y = f2bf(v.y - bf2f(hh.y));
                hh.z = f2bf(v.z); ll.z = f2bf(v.z - bf2f(hh.z));
                hh.w = f2bf(v.w); ll.w = f2bf(v.w - bf2f(hh.w));
                int o = xsw(r, c);
                *(ushort4*)&xh[o] = hh;
                *(ushort4*)&xl[o] = ll;
            }
        } else {
            #pragma unroll
            for (int i = 0; i < 8; ++i) {
                int o = xsw(r, c0 + i * 4);
                *(ushort4*)&xh[o] = make_ushort4(0, 0, 0, 0);
                *(ushort4*)&xl[o] = make_ushort4(0, 0, 0, 0);
            }
        }
    }
    __syncthreads();

    int wid = threadIdx.x >> 6;
    int lane = threadIdx.x & 63;
    int nl = lane & 15;
    int g = lane >> 4;
    int arow = wid * 16 + nl;

    f32x4 acc[8];
    #pragma unroll
    for (int c = 0; c < 8; ++c) acc[c] = (f32x4){0.f, 0.f, 0.f, 0.f};

    #pragma unroll
    for (int t = 0; t < 4; ++t) {
        int ao = xsw(arow, t * 32 + g * 8);
        short8v ah = *(const short8v*)&xh[ao];
        short8v al = *(const short8v*)&xl[ao];
        #pragma unroll
        for (int c = 0; c < 8; ++c) {
            int bo = (((c * 4 + t) * 64) + lane) * 8;
            short8v bh = *(const short8v*)&WBh[bo];
            short8v bl = *(const short8v*)&WBl[bo];
            acc[c] = __builtin_amdgcn_mfma_f32_16x16x32_bf16(ah, bh, acc[c], 0, 0, 0);
            acc[c] = __builtin_amdgcn_mfma_f32_16x16x32_bf16(ah, bl, acc[c], 0, 0, 0);
            acc[c] = __builtin_amdgcn_mfma_f32_16x16x32_bf16(al, bh, acc[c], 0, 0, 0);
        }
    }

    float asv[8], adv[8];
    #pragma unroll
    for (int c = 0; c < 8; ++c) {
        asv[c] = a_s[c * 16 + nl];
        adv[c] = a_d[c * 16 + nl];
    }
    int Rb = bid * 64 + wid * 16 + g * 4;
    #pragma unroll
    for (int r = 0; r < 4; ++r) {
        int R = Rb + r;
        bool ok = (R < Nrows);
        float ps = 0.f, pd = 0.f;
        #pragma unroll
        for (int c = 0; c < 8; ++c) {
            float v = acc[c][r];
            if (ok) outb[(size_t)R * 128 + c * 16 + nl] = f2bf(v);
            ps = fmaf(v, asv[c], ps);
            pd = fmaf(v, adv[c], pd);
        }
        #pragma unroll
        for (int o = 8; o; o >>= 1) {
            ps += __shfl_xor(ps, o);
            pd += __shfl_xor(pd, o);
        }
        if (ok && nl == 0) {
            as_[R] = ps;
            ad_[R] = pd;
        }
    }
}

// ---- layer-1 gemm ∥ bucket histogram; last hist block performs the scans ----
__global__ __launch_bounds__(THREADS) void k_gemm_hist(const float* __restrict__ X,
                                                       const int* __restrict__ idx,
                                                       const unsigned short* __restrict__ WBh,
                                                       const unsigned short* __restrict__ WBl,
                                                       const float* __restrict__ a_s,
                                                       const float* __restrict__ a_d,
                                                       unsigned short* __restrict__ outb,
                                                       float* __restrict__ as_,
                                                       float* __restrict__ ad_,
                                                       int Nrows, int gemm_blocks,
                                                       const int* __restrict__ dst,
                                                       int* __restrict__ bcount,
                                                       int E_, int chunk,
                                                       int* __restrict__ done,
                                                       int* __restrict__ sbase,
                                                       int* __restrict__ gcur,
                                                       int* __restrict__ cbase,
                                                       int nbuk, int Nn) {
    __shared__ unsigned short xh[64 * 128];
    __shared__ unsigned short xl[64 * 128];
    if ((int)blockIdx.x >= gemm_blocks) {
        int hbk = blockIdx.x - gemm_blocks;
        int tid = threadIdx.x;
        __shared__ int hist[THREADS];
        hist[tid] = 0;
        __syncthreads();
        int e0 = hbk * chunk;
        int e1 = min(e0 + chunk, E_);
        for (int e = e0 + tid; e < e1; e += THREADS)
            atomicAdd(&hist[dst[e] / BUK_S], 1);
        __syncthreads();
        int c = hist[tid];
        if (c) atomicAdd(&bcount[tid], c);
        __threadfence();
        __syncthreads();
        __shared__ int lastf;
        if (tid == 0) lastf = (atomicAdd(done, 1) == SORT_BLOCKS - 1);
        __syncthreads();
        if (!lastf) return;
        __threadfence();
        // scans (sole surviving block; bcount via device-scope atomic loads)
        __shared__ int s2[THREADS];
        int v = 0;
        if (tid < nbuk) v = __hip_atomic_load(&bcount[tid], __ATOMIC_RELAXED, __HIP_MEMORY_SCOPE_AGENT);
        s2[tid] = v;
        __syncthreads();
        for (int off = 1; off < THREADS; off <<= 1) {
            int t = (tid >= off) ? s2[tid - off] : 0;
            __syncthreads();
            s2[tid] += t;
            __syncthreads();
        }
        int excl1 = s2[tid] - v;
        if (tid < nbuk) { sbase[tid] = excl1; gcur[tid] = excl1; }
        int n0 = tid * BUK_S;
        int ns = (tid < nbuk) ? min(BUK_S, Nn - n0) : 0;
        int v2 = v + ns;
        __syncthreads();
        s2[tid] = v2;
        __syncthreads();
        for (int off = 1; off < THREADS; off <<= 1) {
            int t = (tid >= off) ? s2[tid - off] : 0;
            __syncthreads();
            s2[tid] += t;
            __syncthreads();
        }
        if (tid < nbuk) cbase[tid] = s2[tid] - v2;
        return;
    }
    gemm_body(xh, xl, X, idx, WBh, WBl, a_s, a_d, outb, as_, ad_, Nrows, blockIdx.x);
}

// ---- plain layer-2 gemm ----
__global__ __launch_bounds__(THREADS) void k_gemm_mfma(const float* __restrict__ X,
                                                       const unsigned short* __restrict__ WBh,
                                                       const unsigned short* __restrict__ WBl,
                                                       const float* __restrict__ a_s,
                                                       const float* __restrict__ a_d,
                                                       unsigned short* __restrict__ outb,
                                                       float* __restrict__ as_,
                                                       float* __restrict__ ad_, int Nrows) {
    __shared__ unsigned short xh[64 * 128];
    __shared__ unsigned short xl[64 * 128];
    gemm_body(xh, xl, X, nullptr, WBh, WBl, a_s, a_d, outb, as_, ad_, Nrows, blockIdx.x);
}

// ---- coarse scatter of packed records into bucket staging ----
__global__ __launch_bounds__(THREADS) void k_bukscatter(const int* __restrict__ src,
                                                        const int* __restrict__ dst,
                                                        int* __restrict__ gcur,
                                                        unsigned int* __restrict__ rec,
                                                        int E_, int chunk) {
    __shared__ int hist[THREADS];
    __shared__ int base[THREADS];
    hist[threadIdx.x] = 0;
    __syncthreads();
    int e0 = blockIdx.x * chunk;
    int e1 = min(e0 + chunk, E_);
    for (int e = e0 + threadIdx.x; e < e1; e += THREADS)
        atomicAdd(&hist[dst[e] / BUK_S], 1);
    __syncthreads();
    int c = hist[threadIdx.x];
    if (c) base[threadIdx.x] = atomicAdd(&gcur[threadIdx.x], c);
    hist[threadIdx.x] = 0;
    __syncthreads();
    for (int e = e0 + threadIdx.x; e < e1; e += THREADS) {
        int d = dst[e];
        int b = d / BUK_S;
        int r = atomicAdd(&hist[b], 1);
        rec[base[b] + r] = (unsigned int)src[e] | ((unsigned int)(d - b * BUK_S) << 17);
    }
}

// ---- per-bucket fine pass -> rowptr + esrc (self-loop last slot) ----
__global__ __launch_bounds__(THREADS) void k_csr(const unsigned int* __restrict__ rec,
                                                 const int* __restrict__ sbase,
                                                 const int* __restrict__ bcount,
                                                 const int* __restrict__ cbase,
                                                 int* __restrict__ rowptr,
                                                 int* __restrict__ esrc,
                                                 int Nn, int nbuk, int Etot) {
    __shared__ int cnt[THREADS];
    __shared__ int s[THREADS];
    __shared__ int cur[THREADS];
    int b = blockIdx.x;
    int tid = threadIdx.x;
    int n0 = b * BUK_S;
    int ns = min(BUK_S, Nn - n0);
    int cnt_e = bcount[b];
    int rbase = sbase[b];
    int cb = cbase[b];

    cnt[tid] = 0;
    __syncthreads();
    for (int i = tid; i < cnt_e; i += THREADS)
        atomicAdd(&cnt[rec[rbase + i] >> 17], 1);
    __syncthreads();
    int v = (tid < ns) ? cnt[tid] + 1 : 0;   // +1 self-loop
    s[tid] = v;
    __syncthreads();
    for (int off = 1; off < THREADS; off <<= 1) {
        int t = (tid >= off) ? s[tid - off] : 0;
        __syncthreads();
        s[tid] += t;
        __syncthreads();
    }
    int excl = s[tid] - v;
    __syncthreads();
    s[tid] = excl;
    cur[tid] = excl;
    if (tid < ns) rowptr[n0 + tid] = cb + excl;
    if (b == nbuk - 1 && tid == 0) rowptr[Nn] = Etot;
    __syncthreads();
    for (int i = tid; i < cnt_e; i += THREADS) {
        unsigned int r = rec[rbase + i];
        int l = r >> 17;
        int slot = atomicAdd(&cur[l], 1);
        esrc[cb + slot] = (int)(r & 0x1FFFFu);
    }
    __syncthreads();
    if (tid < ns) esrc[cb + s[tid] + cnt[tid]] = n0 + tid;   // self-loop last
}

// wave per dst node, fused attention-coef + aggregation.
__global__ __launch_bounds__(THREADS) void k_agg(const unsigned short* __restrict__ hb,
                                                 const float* __restrict__ as_,
                                                 const float* __restrict__ ad_,
                                                 const int* __restrict__ rowptr,
                                                 const int* __restrict__ esrc,
                                                 const float* __restrict__ bias,
                                                 float* __restrict__ out, int Nn) {
    __shared__ int2 ep[4][64];
    int w = threadIdx.x >> 6;
    int lane = threadIdx.x & 63;
    int half = lane >> 5;    // which edge of the pair
    int j = lane & 31;       // dim group (4 dims per lane)
    int d = blockIdx.x * 4 + w;
    if (d >= Nn) return;
    int beg = rowptr[d], end = rowptr[d + 1];
    float adv = ad_[d];
    float z = 0.f, a0 = 0.f, a1 = 0.f, a2 = 0.f, a3 = 0.f;
    for (int c0 = beg; c0 < end; c0 += 64) {
        int kk = c0 + lane;
        bool ok = (kk < end);
        int sl = esrc[ok ? kk : beg];
        float pv = 0.f;
        if (ok) {
            float e = as_[sl] + adv;
            e = (e > 0.f) ? e : 0.2f * e;
            pv = __expf(e);
        }
        ep[w][lane] = make_int2(sl, __float_as_int(pv));
        int cn = end - c0;
        if (cn > 64) cn = 64;
        for (int k0 = 0; k0 < cn; k0 += 16) {
            int2 ev[8];
            #pragma unroll
            for (int i = 0; i < 8; ++i)
                ev[i] = ep[w][(k0 + 2 * i + half) & 63];   // p=0 past cn
            uint2 hv[8];
            #pragma unroll
            for (int i = 0; i < 8; ++i)
                hv[i] = *(const uint2*)&hb[((size_t)ev[i].x << 7) + j * 4];
            #pragma unroll
            for (int i = 0; i < 8; ++i) {
                float p = __int_as_float(ev[i].y);
                z += p;
                a0 += p * __uint_as_float(hv[i].x << 16);
                a1 += p * __uint_as_float(hv[i].x & 0xffff0000u);
                a2 += p * __uint_as_float(hv[i].y << 16);
                a3 += p * __uint_as_float(hv[i].y & 0xffff0000u);
            }
        }
    }
    z  += __shfl_xor(z, 32);
    a0 += __shfl_xor(a0, 32);
    a1 += __shfl_xor(a1, 32);
    a2 += __shfl_xor(a2, 32);
    a3 += __shfl_xor(a3, 32);
    if (half == 0) {
        float inv = 1.f / z;
        float4 o;
        o.x = fmaxf(a0 * inv + bias[j * 4 + 0], 0.f);
        o.y = fmaxf(a1 * inv + bias[j * 4 + 1], 0.f);
        o.z = fmaxf(a2 * inv + bias[j * 4 + 2], 0.f);
        o.w = fmaxf(a3 * inv + bias[j * 4 + 3], 0.f);
        *(float4*)&out[(size_t)d * 128 + j * 4] = o;
    }
}

// phase 1: grid (G, PSLICE); each block sums a strided slice of graph g's rows
__global__ __launch_bounds__(THREADS) void k_pool_partial(const float* __restrict__ x,
                                                          const int* __restrict__ batch,
                                                          float* __restrict__ part, int Nn) {
    int g = blockIdx.x;
    int s = blockIdx.y;
    int a = 0, b = Nn;
    while (a < b) { int mid = (a + b) >> 1; if (batch[mid] < g) a = mid + 1; else b = mid; }
    int lo = a;
    b = Nn;
    while (a < b) { int mid = (a + b) >> 1; if (batch[mid] < g + 1) a = mid + 1; else b = mid; }
    int hi = a;

    int j = threadIdx.x & 127;
    int half = threadIdx.x >> 7;
    float acc = 0.f;
    for (int n = lo + s * 2 + half; n < hi; n += 2 * PSLICE) acc += x[(size_t)n * 128 + j];
    __shared__ float sred[THREADS];
    sred[threadIdx.x] = acc;
    __syncthreads();
    if (half == 0) part[((size_t)g * PSLICE + s) * 128 + j] = sred[j] + sred[128 + j];
}

// phase 2: one block (128 threads) per graph: reduce partials, mean, logits
__global__ __launch_bounds__(128) void k_pool_final(const float* __restrict__ part,
                                                    const int* __restrict__ batch,
                                                    const float* __restrict__ Wc,
                                                    const float* __restrict__ bc,
                                                    float* __restrict__ out, int Nn, int Gn) {
    int g = blockIdx.x;
    int j = threadIdx.x;
    int a = 0, b = Nn;
    while (a < b) { int mid = (a + b) >> 1; if (batch[mid] < g) a = mid + 1; else b = mid; }
    int lo = a;
    b = Nn;
    while (a < b) { int mid = (a + b) >> 1; if (batch[mid] < g + 1) a = mid + 1; else b = mid; }
    int cnt = a - lo;

    float s = 0.f;
    #pragma unroll
    for (int t = 0; t < PSLICE; ++t) s += part[((size_t)g * PSLICE + t) * 128 + j];
    float mean = s / fmaxf((float)cnt, 1.f);
    out[Gn + (size_t)g * 128 + j] = mean;

    __shared__ float sred[128];
    sred[j] = mean * Wc[j];
    __syncthreads();
    for (int off = 64; off >= 1; off >>= 1) {
        if (j < off) sred[j] += sred[j + off];
        __syncthreads();
    }
    if (j == 0) out[g] = sred[0] + bc[0];
}

static inline size_t align256(size_t x) { return (x + 255) & ~(size_t)255; }

extern "C" void kernel_launch(void* const* d_in, const int* in_sizes, int n_in,
                              void* d_out, int out_size, void* d_ws, size_t ws_size,
                              hipStream_t stream) {
    const int* x_lex = (const int*)d_in[0];
    const int* eidx  = (const int*)d_in[1];
    const int* batch = (const int*)d_in[2];
    const float* emb = (const float*)d_in[3];
    const float* W1  = (const float*)d_in[4];
    const float* a_s1 = (const float*)d_in[5];
    const float* a_d1 = (const float*)d_in[6];
    const float* b1  = (const float*)d_in[7];
    const float* W2  = (const float*)d_in[8];
    const float* a_s2 = (const float*)d_in[9];
    const float* a_d2 = (const float*)d_in[10];
    const float* b2  = (const float*)d_in[11];
    const float* Wc  = (const float*)d_in[12];
    const float* bc  = (const float*)d_in[13];

    const int N = in_sizes[0];
    const int E = in_sizes[1] / 2;
    const int G = out_size / 129;      // out = [G logits] + [G x 128 pool]
    const int Etot = E + N;
    const int* esrc_in = eidx;
    const int* edst_in = eidx + E;
    const int NBUK = (N + BUK_S - 1) / BUK_S;   // 256 for N=50000

    // workspace carve
    char* p = (char*)d_ws;
    unsigned short* hb = (unsigned short*)p;  p += align256((size_t)N * 128 * 2);
    float* obuf = (float*)p;            p += align256((size_t)N * 128 * 4);
    float* as_  = (float*)p;            p += align256((size_t)N * 4);
    float* ad_  = (float*)p;            p += align256((size_t)N * 4);
    int* bcount = (int*)p;              p += align256((size_t)NBUK * 4);
    int* sbase  = (int*)p;              p += align256((size_t)NBUK * 4);
    int* gcur   = (int*)p;              p += align256((size_t)NBUK * 4);
    int* cbase  = (int*)p;              p += align256((size_t)NBUK * 4);
    int* done   = (int*)p;              p += align256(256);
    int* rowptr = (int*)p;              p += align256((size_t)(N + 1) * 4);
    unsigned int* rec = (unsigned int*)p; p += align256((size_t)Etot * 4);
    int* esrc   = (int*)p;              p += align256((size_t)Etot * 4);
    float* part = (float*)p;            p += align256((size_t)G * PSLICE * 128 * 4);
    unsigned short* WBh1 = (unsigned short*)p; p += align256((size_t)128 * 128 * 2);
    unsigned short* WBl1 = (unsigned short*)p; p += align256((size_t)128 * 128 * 2);
    unsigned short* WBh2 = (unsigned short*)p; p += align256((size_t)128 * 128 * 2);
    unsigned short* WBl2 = (unsigned short*)p; p += align256((size_t)128 * 128 * 2);

    const int chunk = (E + SORT_BLOCKS - 1) / SORT_BLOCKS;
    const int gemm_grid = (N + 63) / 64;
    const int agg_grid = (N + 3) / 4;

    // 1. prep: W split + zero counters
    k_prep<<<128, THREADS, 0, stream>>>(W1, W2, WBh1, WBl1, WBh2, WBl2, bcount, NBUK, done);

    // 2. layer-1 gemm ∥ bucket hist (+ last-block scan)
    k_gemm_hist<<<gemm_grid + SORT_BLOCKS, THREADS, 0, stream>>>(
        emb, x_lex, WBh1, WBl1, a_s1, a_d1, hb, as_, ad_, N, gemm_grid,
        edst_in, bcount, E, chunk, done, sbase, gcur, cbase, NBUK, N);

    // 3-4. CSR build
    k_bukscatter<<<SORT_BLOCKS, THREADS, 0, stream>>>(esrc_in, edst_in, gcur, rec, E, chunk);
    k_csr<<<NBUK, THREADS, 0, stream>>>(rec, sbase, bcount, cbase, rowptr, esrc, N, NBUK, Etot);

    // 5. layer-1 agg
    k_agg<<<agg_grid, THREADS, 0, stream>>>(hb, as_, ad_, rowptr, esrc, b1, obuf, N);

    // 6-7. layer 2
    k_gemm_mfma<<<gemm_grid, THREADS, 0, stream>>>(obuf, WBh2, WBl2, a_s2, a_d2, hb, as_, ad_, N);
    k_agg<<<agg_grid, THREADS, 0, stream>>>(hb, as_, ad_, rowptr, esrc, b2, obuf, N);

    // 8-9. pool + logits
    k_pool_partial<<<dim3(G, PSLICE), THREADS, 0, stream>>>(obuf, batch, part, N);
    k_pool_final<<<G, 128, 0, stream>>>(part, batch, Wc, bc, (float*)d_out, N, G);
}

// Round 15
// 175.524 us; speedup vs baseline: 1.4465x; 1.0787x over previous
//
#include <hip/hip_runtime.h>
#include <hip/hip_bf16.h>

// ---------------------------------------------------------------------------
// GAT 2-layer forward on MI355X.  11 dispatches (R12 structure).
//   k_prep: W split (both layers, fragment-major) + zero bcount
//   k_bukhist -> k_bukscan -> k_bukscatter -> k_csr : CSR build
//   per layer: k_gemm (2-term split-bf16 MFMA: xh*Wh + xh*Wl, fused att dots)
//              k_agg  (fused att-coef + paired-edge uint2 h gather)
//   k_pool_partial + k_pool_final: pooling + logits
//   Lessons kept: no hipMemset (R10); no per-block device-fence fusions (R13);
//   no gemm∥hist fusion (R14: +9-18 us net loss).
// ---------------------------------------------------------------------------

#define THREADS 256
#define PSLICE 16
#define BUK_S 196        // nodes per bucket (NBUK = 256 for N=50000)
#define SORT_BLOCKS 128

typedef __attribute__((ext_vector_type(8))) short short8v;   // 8 bf16
typedef __attribute__((ext_vector_type(4))) float f32x4;

static __device__ __forceinline__ unsigned short f2bf(float f) {
    unsigned int u = __float_as_uint(f);
    return (unsigned short)((u + 0x7fffu + ((u >> 16) & 1u)) >> 16);  // RNE
}
static __device__ __forceinline__ float bf2f(unsigned short b) {
    return __uint_as_float(((unsigned int)b) << 16);
}

// ---- prep: W split + fragment-major reorder (both layers) + zero bcount ----
// WB[((c*4+t)*64 + lane)*8 + j] ; value = W[k][n], k=t*32+(lane>>4)*8+j, n=c*16+(lane&15)
__global__ __launch_bounds__(THREADS) void k_prep(const float* __restrict__ W1,
                                                  const float* __restrict__ W2,
                                                  unsigned short* __restrict__ Wh1,
                                                  unsigned short* __restrict__ Wl1,
                                                  unsigned short* __restrict__ Wh2,
                                                  unsigned short* __restrict__ Wl2,
                                                  int* __restrict__ bcount, int nbuk) {
    if (blockIdx.x == 0 && threadIdx.x < nbuk) bcount[threadIdx.x] = 0;
    int t = blockIdx.x * THREADS + threadIdx.x;
    const float* W = W1;
    unsigned short* Wh = Wh1;
    unsigned short* Wl = Wl1;
    if (t >= 128 * 128) {
        t -= 128 * 128;
        W = W2; Wh = Wh2; Wl = Wl2;
    }
    int k = t >> 7, n = t & 127;
    float w = W[t];
    unsigned short h = f2bf(w);
    unsigned short lo = f2bf(w - bf2f(h));
    int c = n >> 4, nl = n & 15, tt = k >> 5, kk = k & 31, g = kk >> 3, j = kk & 7;
    int o = (((c * 4 + tt) * 64) + g * 16 + nl) * 8 + j;
    Wh[o] = h;
    Wl[o] = lo;
}

// ---- bucket sort pass A: per-bucket edge counts (LDS-staged) ----
__global__ __launch_bounds__(THREADS) void k_bukhist(const int* __restrict__ dst,
                                                     int* __restrict__ bcount, int E_, int chunk) {
    __shared__ int hist[THREADS];
    hist[threadIdx.x] = 0;
    __syncthreads();
    int e0 = blockIdx.x * chunk;
    int e1 = min(e0 + chunk, E_);
    for (int e = e0 + threadIdx.x; e < e1; e += THREADS)
        atomicAdd(&hist[dst[e] / BUK_S], 1);
    __syncthreads();
    int c = hist[threadIdx.x];
    if (c) atomicAdd(&bcount[threadIdx.x], c);
}

// ---- pass B: scan bucket counts -> staging bases + CSR bases (+self-loops) ----
__global__ __launch_bounds__(THREADS) void k_bukscan(const int* __restrict__ bcount,
                                                     int* __restrict__ sbase,
                                                     int* __restrict__ gcur,
                                                     int* __restrict__ cbase,
                                                     int nbuk, int Nn) {
    __shared__ int s[THREADS];
    int tid = threadIdx.x;
    int v = (tid < nbuk) ? bcount[tid] : 0;
    s[tid] = v;
    __syncthreads();
    for (int off = 1; off < THREADS; off <<= 1) {
        int t = (tid >= off) ? s[tid - off] : 0;
        __syncthreads();
        s[tid] += t;
        __syncthreads();
    }
    int excl1 = s[tid] - v;
    if (tid < nbuk) { sbase[tid] = excl1; gcur[tid] = excl1; }
    int n0 = tid * BUK_S;
    int ns = (tid < nbuk) ? min(BUK_S, Nn - n0) : 0;
    int v2 = v + ns;
    __syncthreads();
    s[tid] = v2;
    __syncthreads();
    for (int off = 1; off < THREADS; off <<= 1) {
        int t = (tid >= off) ? s[tid - off] : 0;
        __syncthreads();
        s[tid] += t;
        __syncthreads();
    }
    if (tid < nbuk) cbase[tid] = s[tid] - v2;
}

// ---- pass C: coarse scatter of packed records into bucket staging ----
__global__ __launch_bounds__(THREADS) void k_bukscatter(const int* __restrict__ src,
                                                        const int* __restrict__ dst,
                                                        int* __restrict__ gcur,
                                                        unsigned int* __restrict__ rec,
                                                        int E_, int chunk) {
    __shared__ int hist[THREADS];
    __shared__ int base[THREADS];
    hist[threadIdx.x] = 0;
    __syncthreads();
    int e0 = blockIdx.x * chunk;
    int e1 = min(e0 + chunk, E_);
    for (int e = e0 + threadIdx.x; e < e1; e += THREADS)
        atomicAdd(&hist[dst[e] / BUK_S], 1);
    __syncthreads();
    int c = hist[threadIdx.x];
    if (c) base[threadIdx.x] = atomicAdd(&gcur[threadIdx.x], c);
    hist[threadIdx.x] = 0;
    __syncthreads();
    for (int e = e0 + threadIdx.x; e < e1; e += THREADS) {
        int d = dst[e];
        int b = d / BUK_S;
        int r = atomicAdd(&hist[b], 1);
        rec[base[b] + r] = (unsigned int)src[e] | ((unsigned int)(d - b * BUK_S) << 17);
    }
}

// ---- pass D: per-bucket fine pass -> rowptr + esrc (self-loop last slot) ----
__global__ __launch_bounds__(THREADS) void k_csr(const unsigned int* __restrict__ rec,
                                                 const int* __restrict__ sbase,
                                                 const int* __restrict__ bcount,
                                                 const int* __restrict__ cbase,
                                                 int* __restrict__ rowptr,
                                                 int* __restrict__ esrc,
                                                 int Nn, int nbuk, int Etot) {
    __shared__ int cnt[THREADS];
    __shared__ int s[THREADS];
    __shared__ int cur[THREADS];
    int b = blockIdx.x;
    int tid = threadIdx.x;
    int n0 = b * BUK_S;
    int ns = min(BUK_S, Nn - n0);
    int cnt_e = bcount[b];
    int rbase = sbase[b];
    int cb = cbase[b];

    cnt[tid] = 0;
    __syncthreads();
    for (int i = tid; i < cnt_e; i += THREADS)
        atomicAdd(&cnt[rec[rbase + i] >> 17], 1);
    __syncthreads();
    int v = (tid < ns) ? cnt[tid] + 1 : 0;   // +1 self-loop
    s[tid] = v;
    __syncthreads();
    for (int off = 1; off < THREADS; off <<= 1) {
        int t = (tid >= off) ? s[tid - off] : 0;
        __syncthreads();
        s[tid] += t;
        __syncthreads();
    }
    int excl = s[tid] - v;
    __syncthreads();
    s[tid] = excl;
    cur[tid] = excl;
    if (tid < ns) rowptr[n0 + tid] = cb + excl;
    if (b == nbuk - 1 && tid == 0) rowptr[Nn] = Etot;
    __syncthreads();
    for (int i = tid; i < cnt_e; i += THREADS) {
        unsigned int r = rec[rbase + i];
        int l = r >> 17;
        int slot = atomicAdd(&cur[l], 1);
        esrc[cb + slot] = (int)(r & 0x1FFFFu);
    }
    __syncthreads();
    if (tid < ns) esrc[cb + s[tid] + cnt[tid]] = n0 + tid;   // self-loop last
}

// swizzled LDS index (ushort units) for x tiles
static __device__ __forceinline__ int xsw(int r, int c) {
    return (((r * 16 + (c >> 3)) ^ (r & 7)) << 3) | (c & 7);
}

// H = X(gathered) @ W via MFMA 2-term split-bf16 (xh*Wh + xh*Wl; x rounded
// once to bf16 — dropped xl*Wh term is ~5e-5 abs, same order as bf16 h
// storage). 64 rows x 128 cols per block, 4 waves x 16 rows x 8 col-tiles.
__global__ __launch_bounds__(THREADS) void k_gemm(const float* __restrict__ X,
                                                  const int* __restrict__ idx,
                                                  const unsigned short* __restrict__ WBh,
                                                  const unsigned short* __restrict__ WBl,
                                                  const float* __restrict__ a_s,
                                                  const float* __restrict__ a_d,
                                                  unsigned short* __restrict__ outb,
                                                  float* __restrict__ as_,
                                                  float* __restrict__ ad_, int Nrows) {
    __shared__ unsigned short xh[64 * 128];   // 16 KB

    {
        int r = threadIdx.x >> 2;            // 0..63
        int c0 = (threadIdx.x & 3) * 32;
        int R = blockIdx.x * 64 + r;
        if (R < Nrows) {
            int g = idx ? idx[R] : R;
            const float4* xrow = (const float4*)(X + (size_t)g * 128);
            #pragma unroll
            for (int i = 0; i < 8; ++i) {
                float4 v = xrow[(c0 >> 2) + i];
                ushort4 hh;
                hh.x = f2bf(v.x);
                hh.y = f2bf(v.y);
                hh.z = f2bf(v.z);
                hh.w = f2bf(v.w);
                *(ushort4*)&xh[xsw(r, c0 + i * 4)] = hh;
            }
        } else {
            #pragma unroll
            for (int i = 0; i < 8; ++i)
                *(ushort4*)&xh[xsw(r, c0 + i * 4)] = make_ushort4(0, 0, 0, 0);
        }
    }
    __syncthreads();

    int wid = threadIdx.x >> 6;
    int lane = threadIdx.x & 63;
    int nl = lane & 15;
    int g = lane >> 4;
    int arow = wid * 16 + nl;

    f32x4 acc[8];
    #pragma unroll
    for (int c = 0; c < 8; ++c) acc[c] = (f32x4){0.f, 0.f, 0.f, 0.f};

    #pragma unroll
    for (int t = 0; t < 4; ++t) {
        short8v ah = *(const short8v*)&xh[xsw(arow, t * 32 + g * 8)];
        #pragma unroll
        for (int c = 0; c < 8; ++c) {
            int bo = (((c * 4 + t) * 64) + lane) * 8;
            short8v bh = *(const short8v*)&WBh[bo];
            short8v bl = *(const short8v*)&WBl[bo];
            acc[c] = __builtin_amdgcn_mfma_f32_16x16x32_bf16(ah, bh, acc[c], 0, 0, 0);
            acc[c] = __builtin_amdgcn_mfma_f32_16x16x32_bf16(ah, bl, acc[c], 0, 0, 0);
        }
    }

    float asv[8], adv[8];
    #pragma unroll
    for (int c = 0; c < 8; ++c) {
        asv[c] = a_s[c * 16 + nl];
        adv[c] = a_d[c * 16 + nl];
    }
    int Rb = blockIdx.x * 64 + wid * 16 + g * 4;
    #pragma unroll
    for (int r = 0; r < 4; ++r) {
        int R = Rb + r;
        bool ok = (R < Nrows);
        float ps = 0.f, pd = 0.f;
        #pragma unroll
        for (int c = 0; c < 8; ++c) {
            float v = acc[c][r];
            if (ok) outb[(size_t)R * 128 + c * 16 + nl] = f2bf(v);
            ps = fmaf(v, asv[c], ps);
            pd = fmaf(v, adv[c], pd);
        }
        #pragma unroll
        for (int o = 8; o; o >>= 1) {
            ps += __shfl_xor(ps, o);
            pd += __shfl_xor(pd, o);
        }
        if (ok && nl == 0) {
            as_[R] = ps;
            ad_[R] = pd;
        }
    }
}

// wave per dst node, fused attention-coef + aggregation.
__global__ __launch_bounds__(THREADS) void k_agg(const unsigned short* __restrict__ hb,
                                                 const float* __restrict__ as_,
                                                 const float* __restrict__ ad_,
                                                 const int* __restrict__ rowptr,
                                                 const int* __restrict__ esrc,
                                                 const float* __restrict__ bias,
                                                 float* __restrict__ out, int Nn) {
    __shared__ int2 ep[4][64];
    int w = threadIdx.x >> 6;
    int lane = threadIdx.x & 63;
    int half = lane >> 5;    // which edge of the pair
    int j = lane & 31;       // dim group (4 dims per lane)
    int d = blockIdx.x * 4 + w;
    if (d >= Nn) return;
    int beg = rowptr[d], end = rowptr[d + 1];
    float adv = ad_[d];
    float z = 0.f, a0 = 0.f, a1 = 0.f, a2 = 0.f, a3 = 0.f;
    for (int c0 = beg; c0 < end; c0 += 64) {
        int kk = c0 + lane;
        bool ok = (kk < end);
        int sl = esrc[ok ? kk : beg];
        float pv = 0.f;
        if (ok) {
            float e = as_[sl] + adv;
            e = (e > 0.f) ? e : 0.2f * e;
            pv = __expf(e);
        }
        ep[w][lane] = make_int2(sl, __float_as_int(pv));
        int cn = end - c0;
        if (cn > 64) cn = 64;
        for (int k0 = 0; k0 < cn; k0 += 16) {
            int2 ev[8];
            #pragma unroll
            for (int i = 0; i < 8; ++i)
                ev[i] = ep[w][(k0 + 2 * i + half) & 63];   // p=0 past cn
            uint2 hv[8];
            #pragma unroll
            for (int i = 0; i < 8; ++i)
                hv[i] = *(const uint2*)&hb[((size_t)ev[i].x << 7) + j * 4];
            #pragma unroll
            for (int i = 0; i < 8; ++i) {
                float p = __int_as_float(ev[i].y);
                z += p;
                a0 += p * __uint_as_float(hv[i].x << 16);
                a1 += p * __uint_as_float(hv[i].x & 0xffff0000u);
                a2 += p * __uint_as_float(hv[i].y << 16);
                a3 += p * __uint_as_float(hv[i].y & 0xffff0000u);
            }
        }
    }
    z  += __shfl_xor(z, 32);
    a0 += __shfl_xor(a0, 32);
    a1 += __shfl_xor(a1, 32);
    a2 += __shfl_xor(a2, 32);
    a3 += __shfl_xor(a3, 32);
    if (half == 0) {
        float inv = 1.f / z;
        float4 o;
        o.x = fmaxf(a0 * inv + bias[j * 4 + 0], 0.f);
        o.y = fmaxf(a1 * inv + bias[j * 4 + 1], 0.f);
        o.z = fmaxf(a2 * inv + bias[j * 4 + 2], 0.f);
        o.w = fmaxf(a3 * inv + bias[j * 4 + 3], 0.f);
        *(float4*)&out[(size_t)d * 128 + j * 4] = o;
    }
}

// phase 1: grid (G, PSLICE); each block sums a strided slice of graph g's rows
__global__ __launch_bounds__(THREADS) void k_pool_partial(const float* __restrict__ x,
                                                          const int* __restrict__ batch,
                                                          float* __restrict__ part, int Nn) {
    int g = blockIdx.x;
    int s = blockIdx.y;
    int a = 0, b = Nn;
    while (a < b) { int mid = (a + b) >> 1; if (batch[mid] < g) a = mid + 1; else b = mid; }
    int lo = a;
    b = Nn;
    while (a < b) { int mid = (a + b) >> 1; if (batch[mid] < g + 1) a = mid + 1; else b = mid; }
    int hi = a;

    int j = threadIdx.x & 127;
    int half = threadIdx.x >> 7;
    float acc = 0.f;
    for (int n = lo + s * 2 + half; n < hi; n += 2 * PSLICE) acc += x[(size_t)n * 128 + j];
    __shared__ float sred[THREADS];
    sred[threadIdx.x] = acc;
    __syncthreads();
    if (half == 0) part[((size_t)g * PSLICE + s) * 128 + j] = sred[j] + sred[128 + j];
}

// phase 2: one block (128 threads) per graph: reduce partials, mean, logits
__global__ __launch_bounds__(128) void k_pool_final(const float* __restrict__ part,
                                                    const int* __restrict__ batch,
                                                    const float* __restrict__ Wc,
                                                    const float* __restrict__ bc,
                                                    float* __restrict__ out, int Nn, int Gn) {
    int g = blockIdx.x;
    int j = threadIdx.x;
    int a = 0, b = Nn;
    while (a < b) { int mid = (a + b) >> 1; if (batch[mid] < g) a = mid + 1; else b = mid; }
    int lo = a;
    b = Nn;
    while (a < b) { int mid = (a + b) >> 1; if (batch[mid] < g + 1) a = mid + 1; else b = mid; }
    int cnt = a - lo;

    float s = 0.f;
    #pragma unroll
    for (int t = 0; t < PSLICE; ++t) s += part[((size_t)g * PSLICE + t) * 128 + j];
    float mean = s / fmaxf((float)cnt, 1.f);
    out[Gn + (size_t)g * 128 + j] = mean;

    __shared__ float sred[128];
    sred[j] = mean * Wc[j];
    __syncthreads();
    for (int off = 64; off >= 1; off >>= 1) {
        if (j < off) sred[j] += sred[j + off];
        __syncthreads();
    }
    if (j == 0) out[g] = sred[0] + bc[0];
}

static inline size_t align256(size_t x) { return (x + 255) & ~(size_t)255; }

extern "C" void kernel_launch(void* const* d_in, const int* in_sizes, int n_in,
                              void* d_out, int out_size, void* d_ws, size_t ws_size,
                              hipStream_t stream) {
    const int* x_lex = (const int*)d_in[0];
    const int* eidx  = (const int*)d_in[1];
    const int* batch = (const int*)d_in[2];
    const float* emb = (const float*)d_in[3];
    const float* W1  = (const float*)d_in[4];
    const float* a_s1 = (const float*)d_in[5];
    const float* a_d1 = (const float*)d_in[6];
    const float* b1  = (const float*)d_in[7];
    const float* W2  = (const float*)d_in[8];
    const float* a_s2 = (const float*)d_in[9];
    const float* a_d2 = (const float*)d_in[10];
    const float* b2  = (const float*)d_in[11];
    const float* Wc  = (const float*)d_in[12];
    const float* bc  = (const float*)d_in[13];

    const int N = in_sizes[0];
    const int E = in_sizes[1] / 2;
    const int G = out_size / 129;      // out = [G logits] + [G x 128 pool]
    const int Etot = E + N;
    const int* esrc_in = eidx;
    const int* edst_in = eidx + E;
    const int NBUK = (N + BUK_S - 1) / BUK_S;   // 256 for N=50000

    // workspace carve
    char* p = (char*)d_ws;
    unsigned short* hb = (unsigned short*)p;  p += align256((size_t)N * 128 * 2);
    float* obuf = (float*)p;            p += align256((size_t)N * 128 * 4);
    float* as_  = (float*)p;            p += align256((size_t)N * 4);
    float* ad_  = (float*)p;            p += align256((size_t)N * 4);
    int* bcount = (int*)p;              p += align256((size_t)NBUK * 4);
    int* sbase  = (int*)p;              p += align256((size_t)NBUK * 4);
    int* gcur   = (int*)p;              p += align256((size_t)NBUK * 4);
    int* cbase  = (int*)p;              p += align256((size_t)NBUK * 4);
    int* rowptr = (int*)p;              p += align256((size_t)(N + 1) * 4);
    unsigned int* rec = (unsigned int*)p; p += align256((size_t)Etot * 4);
    int* esrc   = (int*)p;              p += align256((size_t)Etot * 4);
    float* part = (float*)p;            p += align256((size_t)G * PSLICE * 128 * 4);
    unsigned short* WBh1 = (unsigned short*)p; p += align256((size_t)128 * 128 * 2);
    unsigned short* WBl1 = (unsigned short*)p; p += align256((size_t)128 * 128 * 2);
    unsigned short* WBh2 = (unsigned short*)p; p += align256((size_t)128 * 128 * 2);
    unsigned short* WBl2 = (unsigned short*)p; p += align256((size_t)128 * 128 * 2);

    const int chunk = (E + SORT_BLOCKS - 1) / SORT_BLOCKS;
    const int gemm_grid = (N + 63) / 64;
    const int agg_grid = (N + 3) / 4;

    // 1. prep: W split + zero bcount
    k_prep<<<128, THREADS, 0, stream>>>(W1, W2, WBh1, WBl1, WBh2, WBl2, bcount, NBUK);

    // 2-5. CSR build via bucket sort
    k_bukhist<<<SORT_BLOCKS, THREADS, 0, stream>>>(edst_in, bcount, E, chunk);
    k_bukscan<<<1, THREADS, 0, stream>>>(bcount, sbase, gcur, cbase, NBUK, N);
    k_bukscatter<<<SORT_BLOCKS, THREADS, 0, stream>>>(esrc_in, edst_in, gcur, rec, E, chunk);
    k_csr<<<NBUK, THREADS, 0, stream>>>(rec, sbase, bcount, cbase, rowptr, esrc, N, NBUK, Etot);

    // 6-7. layer 1
    k_gemm<<<gemm_grid, THREADS, 0, stream>>>(emb, x_lex, WBh1, WBl1, a_s1, a_d1, hb, as_, ad_, N);
    k_agg<<<agg_grid, THREADS, 0, stream>>>(hb, as_, ad_, rowptr, esrc, b1, obuf, N);

    // 8-9. layer 2
    k_gemm<<<gemm_grid, THREADS, 0, stream>>>(obuf, nullptr, WBh2, WBl2, a_s2, a_d2, hb, as_, ad_, N);
    k_agg<<<agg_grid, THREADS, 0, stream>>>(hb, as_, ad_, rowptr, esrc, b2, obuf, N);

    // 10-11. pool + logits
    k_pool_partial<<<dim3(G, PSLICE), THREADS, 0, stream>>>(obuf, batch, part, N);
    k_pool_final<<<G, 128, 0, stream>>>(part, batch, Wc, bc, (float*)d_out, N, G);
}